// Round 13
// baseline (748.649 us; speedup 1.0000x reference)
//
#include <hip/hip_runtime.h>
#include <hip/hip_bf16.h>
#include <cstdint>

#define N_NODES 50000
#define N_EDGES 500000
#define HID 128
#define NLAYERS 4
#define NGRAPHS 64
#define NTILES ((N_NODES + 63) / 64)    // 782  (pq_k)
#define NT32 ((N_NODES + 31) / 32)      // 1563 (upd_k)
#define NPW 4                            // nodes per wave in edge kernel
#define EBLOCKS ((N_NODES + NPW * 4 - 1) / (NPW * 4))   // 3125

typedef float f32x4 __attribute__((ext_vector_type(4)));
typedef __bf16 bf16x8 __attribute__((ext_vector_type(8)));

// ---- scratch in device globals (module-load allocated; d_ws unused) ----
__device__ float          g_h[(size_t)N_NODES * HID];
__device__ unsigned short g_hb[(size_t)N_NODES * HID];
__device__ float          g_S[(size_t)N_NODES * HID];
__device__ unsigned short g_PQ[(size_t)N_NODES * 256];
__device__ int2           g_edge[N_EDGES];              // {src, dist bits}
__device__ int            g_cnt[N_NODES];
__device__ int            g_cursor[N_NODES];
__device__ int            g_bsum[1024];
__device__ unsigned short g_pqw[NLAYERS * 4 * 16 * 64 * 8];
__device__ float          g_wc[NLAYERS * 128 * 128];
__device__ float          g_bc[NLAYERS * 128];
__device__ unsigned short g_uw1p[NLAYERS * 8 * 8 * 64 * 8];
__device__ unsigned short g_uw2p[NLAYERS * 4 * 8 * 64 * 8];
__device__ float          g_pooled[NGRAPHS * HID];

__device__ __forceinline__ unsigned short f2bf(float f) {
    uint32_t u = __builtin_bit_cast(uint32_t, f);
    uint32_t r = (u + 0x7fffu + ((u >> 16) & 1u)) >> 16;
    return (unsigned short)r;
}
__device__ __forceinline__ float bf2f(unsigned short u) {
    return __builtin_bit_cast(float, (uint32_t)u << 16);
}

// ---------------- clears ----------------
__global__ void clear_cnt_k() {
    int i = blockIdx.x * 256 + threadIdx.x;
    if (i < N_NODES) g_cnt[i] = 0;
}
__global__ void clear_pooled_k() {
    int i = blockIdx.x * 256 + threadIdx.x;
    if (i < NGRAPHS * HID) g_pooled[i] = 0.f;
}

// ---------------- weight preprocessing ----------------
__global__ void pack_pqw_k(const float* __restrict__ w1) {
    int lane = threadIdx.x;
    int bid = blockIdx.x;                  // L*64 + ks*16 + nt
    int nt = bid & 15, ks = (bid >> 4) & 3, L = bid >> 6;
    const float* w = w1 + (size_t)L * 257 * HID;
    int kb = ks * 32 + (lane >> 4) * 8;
    int n = nt * 16 + (lane & 15);
    unsigned short tmp[8];
#pragma unroll
    for (int j = 0; j < 8; ++j) {
        int k = kb + j;
        float v = (n < 128) ? w[(size_t)k * HID + n] : w[(size_t)(128 + k) * HID + (n - 128)];
        tmp[j] = f2bf(v);
    }
    uint4 o = make_uint4(tmp[0] | ((uint32_t)tmp[1] << 16), tmp[2] | ((uint32_t)tmp[3] << 16),
                         tmp[4] | ((uint32_t)tmp[5] << 16), tmp[6] | ((uint32_t)tmp[7] << 16));
    *(uint4*)&g_pqw[(((size_t)(L * 4 + ks) * 16 + nt) * 64 + lane) * 8] = o;
}

__global__ void wc_k(const float* __restrict__ mw2, const float* __restrict__ uw1) {
    __shared__ float row[128];
    int L = blockIdx.x >> 7, k = blockIdx.x & 127, j = threadIdx.x;
    row[j] = mw2[(size_t)L * 128 * 128 + k * 128 + j];
    __syncthreads();
    const float* u1b = uw1 + (size_t)L * 256 * 128 + 128 * 128;
    float s = 0.f;
    for (int i = 0; i < 128; ++i) s += row[i] * u1b[i * 128 + j];
    g_wc[(size_t)L * 128 * 128 + k * 128 + j] = s;
}
__global__ void bc_k(const float* __restrict__ mb2, const float* __restrict__ uw1) {
    int L = blockIdx.x, j = threadIdx.x;
    const float* u1b = uw1 + (size_t)L * 256 * 128 + 128 * 128;
    const float* b2 = mb2 + L * 128;
    float s = 0.f;
    for (int i = 0; i < 128; ++i) s += b2[i] * u1b[i * 128 + j];
    g_bc[L * 128 + j] = s;
}

__global__ void pack_u1_k(const float* __restrict__ uw1) {
    int lane = threadIdx.x;
    int bid = blockIdx.x;                  // L*64 + ks*8 + nt
    int nt = bid & 7, ks = (bid >> 3) & 7, L = bid >> 6;
    int kb = ks * 32 + (lane >> 4) * 8;
    int n = nt * 16 + (lane & 15);
    unsigned short tmp[8];
#pragma unroll
    for (int j = 0; j < 8; ++j) {
        int k = kb + j;
        float v = (k < 128) ? uw1[(size_t)L * 256 * 128 + (size_t)k * 128 + n]
                            : g_wc[(size_t)L * 128 * 128 + (size_t)(k - 128) * 128 + n];
        tmp[j] = f2bf(v);
    }
    uint4 o = make_uint4(tmp[0] | ((uint32_t)tmp[1] << 16), tmp[2] | ((uint32_t)tmp[3] << 16),
                         tmp[4] | ((uint32_t)tmp[5] << 16), tmp[6] | ((uint32_t)tmp[7] << 16));
    *(uint4*)&g_uw1p[(((size_t)(L * 8 + ks) * 8 + nt) * 64 + lane) * 8] = o;
}

__global__ void pack_w2_k(const float* __restrict__ uw2) {
    int lane = threadIdx.x;
    int bid = blockIdx.x;                  // L*32 + ks*8 + nt
    int nt = bid & 7, ks = (bid >> 3) & 3, L = bid >> 5;
    int kb = ks * 32 + (lane >> 4) * 8;
    int n = nt * 16 + (lane & 15);
    unsigned short tmp[8];
#pragma unroll
    for (int j = 0; j < 8; ++j)
        tmp[j] = f2bf(uw2[(size_t)L * 128 * 128 + (size_t)(kb + j) * 128 + n]);
    uint4 o = make_uint4(tmp[0] | ((uint32_t)tmp[1] << 16), tmp[2] | ((uint32_t)tmp[3] << 16),
                         tmp[4] | ((uint32_t)tmp[5] << 16), tmp[6] | ((uint32_t)tmp[7] << 16));
    *(uint4*)&g_uw2p[(((size_t)(L * 4 + ks) * 8 + nt) * 64 + lane) * 8] = o;
}

// ---------------- node encoder ----------------
__global__ void encode_k(const float* __restrict__ x, const float* __restrict__ w,
                         const float* __restrict__ b) {
    __shared__ float xl[2][15];
    int t = threadIdx.x;
    int half = t >> 7;
    int node = blockIdx.x * 2 + half;
    int c = t & 127;
    if (c < 15) xl[half][c] = x[(size_t)node * 15 + c];
    __syncthreads();
    float acc = b[c];
#pragma unroll
    for (int k = 0; k < 15; ++k) acc += xl[half][k] * w[k * HID + c];
    g_h[(size_t)node * HID + c] = acc;
    g_hb[(size_t)node * HID + c] = f2bf(acc);
}

// ---------------- counting sort of edges by dst ----------------
__global__ void hist_k(const int* __restrict__ ei) {
    int e = blockIdx.x * 256 + threadIdx.x;
    if (e < N_EDGES) atomicAdd(&g_cnt[ei[N_EDGES + e]], 1);
}
__global__ void scanA_k() {
    __shared__ int s[512];
    int t = threadIdx.x;
    int i = blockIdx.x * 512 + t;
    s[t] = (i < N_NODES) ? g_cnt[i] : 0;
    __syncthreads();
    for (int d = 256; d > 0; d >>= 1) {
        if (t < d) s[t] += s[t + d];
        __syncthreads();
    }
    if (t == 0) g_bsum[blockIdx.x] = s[0];
}
__global__ void scanB_k(int nb) {
    if (threadIdx.x == 0) {
        int acc = 0;
        for (int i = 0; i < nb; ++i) { int v = g_bsum[i]; g_bsum[i] = acc; acc += v; }
    }
}
__global__ void scanC_k() {
    __shared__ int s[512];
    int t = threadIdx.x;
    int i = blockIdx.x * 512 + t;
    int v = (i < N_NODES) ? g_cnt[i] : 0;
    s[t] = v;
    __syncthreads();
    for (int d = 1; d < 512; d <<= 1) {
        int add = (t >= d) ? s[t - d] : 0;
        __syncthreads();
        s[t] += add;
        __syncthreads();
    }
    if (i < N_NODES) g_cursor[i] = g_bsum[blockIdx.x] + s[t] - v;
}
__global__ void scatter_k(const int* __restrict__ ei, const float* __restrict__ pos) {
    int e = blockIdx.x * 256 + threadIdx.x;
    if (e >= N_EDGES) return;
    int s = ei[e];
    int d = ei[N_EDGES + e];
    float dx = pos[d * 3 + 0] - pos[s * 3 + 0];
    float dy = pos[d * 3 + 1] - pos[s * 3 + 1];
    float dz = pos[d * 3 + 2] - pos[s * 3 + 2];
    float dist = sqrtf(dx * dx + dy * dy + dz * dz);
    int p = atomicAdd(&g_cursor[d], 1);
    g_edge[p] = make_int2(s, __builtin_bit_cast(int, dist));   // one 8B store
}
// after scatter_k: g_cursor[n] == end offset; start = end - g_cnt[n].

// ---------------- PQ = hb @ [Wd|Ws]  (standalone, only for layer 0) ----------------
__global__ __launch_bounds__(256, 2)
void pq_k(int L) {
    __shared__ unsigned short Abuf[64 * 128];
    __shared__ unsigned short Obuf[64 * 264];
    const unsigned short* wp = g_pqw + (size_t)L * 4 * 16 * 64 * 8;
    int t = threadIdx.x, wave = t >> 6, lane = t & 63;
    int arow = lane & 15, kgrp = lane >> 4;
    int tile0 = blockIdx.x * 64;

    {
        int r = t >> 2, p = t & 3;
        int n = tile0 + r;
        bool valid = n < N_NODES;
#pragma unroll
        for (int q = 0; q < 4; ++q) {
            int slot = p * 4 + q;
            uint4 v = make_uint4(0, 0, 0, 0);
            if (valid) v = *(const uint4*)&g_hb[(size_t)n * HID + slot * 8];
            *(uint4*)&Abuf[r * 128 + ((slot ^ (r & 7)) << 3)] = v;
        }
    }
    __syncthreads();

    bf16x8 wv[4][4];
#pragma unroll
    for (int ks = 0; ks < 4; ++ks)
#pragma unroll
        for (int ntl = 0; ntl < 4; ++ntl)
            wv[ks][ntl] = *(const bf16x8*)&wp[((size_t)(ks * 16 + wave * 4 + ntl) * 64 + lane) * 8];

    f32x4 acc[4][4];
#pragma unroll
    for (int rf = 0; rf < 4; ++rf)
#pragma unroll
        for (int ntl = 0; ntl < 4; ++ntl) acc[rf][ntl] = (f32x4){0.f, 0.f, 0.f, 0.f};
#pragma unroll
    for (int ks = 0; ks < 4; ++ks) {
        int slot = ks * 4 + kgrp;
#pragma unroll
        for (int rf = 0; rf < 4; ++rf) {
            int row = rf * 16 + arow;
            bf16x8 a = *(const bf16x8*)&Abuf[row * 128 + ((slot ^ (row & 7)) << 3)];
#pragma unroll
            for (int ntl = 0; ntl < 4; ++ntl)
                acc[rf][ntl] = __builtin_amdgcn_mfma_f32_16x16x32_bf16(a, wv[ks][ntl], acc[rf][ntl], 0, 0, 0);
        }
    }
#pragma unroll
    for (int rf = 0; rf < 4; ++rf)
#pragma unroll
        for (int ntl = 0; ntl < 4; ++ntl) {
            int col = wave * 64 + ntl * 16 + arow;
#pragma unroll
            for (int q = 0; q < 4; ++q) {
                int row = rf * 16 + kgrp * 4 + q;
                Obuf[row * 264 + col] = f2bf(acc[rf][ntl][q]);
            }
        }
    __syncthreads();
#pragma unroll
    for (int i = 0; i < 8; ++i) {
        int k = t + i * 256;
        int row = k >> 5, cc = k & 31;
        int n = tile0 + row;
        if (n < N_NODES)
            *(uint4*)&g_PQ[(size_t)n * 256 + cc * 8] = *(const uint4*)&Obuf[row * 264 + cc * 8];
    }
}

// ---------------- edge kernel: S[n] = sum_e relu(P[n]+Q[src]+dist*wl+b1) ----------------
__global__ __launch_bounds__(256, 8)
void edge_relu_k(const float* __restrict__ w1last, const float* __restrict__ b1) {
    int t = threadIdx.x, wave = t >> 6, lane = t & 63;
    int c2 = lane * 2;
    float wl0 = w1last[c2], wl1 = w1last[c2 + 1];
    float bb0 = b1[c2], bb1 = b1[c2 + 1];

    int gw = blockIdx.x * 4 + wave;
    int n0 = gw * NPW;
    int n1 = n0 + NPW < N_NODES ? n0 + NPW : N_NODES;

    for (int n = n0; n < n1; ++n) {
        int end = g_cursor[n];
        int cnt = g_cnt[n];
        int beg = end - cnt;
        uint32_t pv = *(const uint32_t*)&g_PQ[(size_t)n * 256 + c2];
        float pb0 = bf2f((unsigned short)(pv & 0xffff)) + bb0;
        float pb1 = bf2f((unsigned short)(pv >> 16)) + bb1;
        float acc0 = 0.f, acc1 = 0.f;

        for (int cb = beg; cb < end; cb += 64) {
            int mye = cb + lane;
            bool v = mye < end;
            int2 ed = v ? g_edge[mye] : make_int2(0, 0);
            int msrc = ed.x;
            float mdist = __builtin_bit_cast(float, ed.y);
            int lim = end - cb < 64 ? end - cb : 64;
            int full = lim & ~7;
            for (int b = 0; b < full; b += 8) {
                uint32_t qv[8];
#pragma unroll
                for (int j = 0; j < 8; ++j) {
                    int s = __shfl(msrc, b + j);
                    qv[j] = *(const uint32_t*)&g_PQ[(size_t)s * 256 + 128 + c2];
                }
#pragma unroll
                for (int j = 0; j < 8; ++j) {
                    float dist = __shfl(mdist, b + j);
                    acc0 += fmaxf(fmaf(dist, wl0, pb0 + bf2f((unsigned short)(qv[j] & 0xffff))), 0.f);
                    acc1 += fmaxf(fmaf(dist, wl1, pb1 + bf2f((unsigned short)(qv[j] >> 16))), 0.f);
                }
            }
            for (int j = full; j < lim; ++j) {
                int s = __shfl(msrc, j);
                float dist = __shfl(mdist, j);
                uint32_t qv = *(const uint32_t*)&g_PQ[(size_t)s * 256 + 128 + c2];
                acc0 += fmaxf(fmaf(dist, wl0, pb0 + bf2f((unsigned short)(qv & 0xffff))), 0.f);
                acc1 += fmaxf(fmaf(dist, wl1, pb1 + bf2f((unsigned short)(qv >> 16))), 0.f);
            }
        }
        *(float2*)&g_S[(size_t)n * HID + c2] = make_float2(acc0, acc1);
    }
}

// ---------------- fused node update + PQ for next layer (32-row tiles) ----------------
// 4 waves; wave owns cols wave*32..+31 across all 32 rows. LDS ~17.3KB -> high occupancy.
__global__ __launch_bounds__(256, 6)
void upd_k(const float* __restrict__ ub1, const float* __restrict__ ub2,
           const float* __restrict__ lng, const float* __restrict__ lnb,
           int L, int first_layer, int Lpq) {
    __shared__ unsigned short Abuf[32 * 128];   // 8KB: hb -> S -> hn(bf16)
    __shared__ unsigned short Hbuf[32 * 128];   // 8KB: hidden -> f32 h 16-row passes -> PQ halves
    __shared__ float rsums[4][2][32];           // 1KB
    __shared__ float degb[32];
    const unsigned short* w1p = g_uw1p + (size_t)L * 8 * 8 * 64 * 8;
    const unsigned short* w2p = g_uw2p + (size_t)L * 4 * 8 * 64 * 8;
    int t = threadIdx.x, wave = t >> 6, lane = t & 63;
    int arow = lane & 15, kgrp = lane >> 4;
    int tile0 = blockIdx.x * 32;

    int sr = t >> 3, sp = t & 7;     // sr 0..31, sp 0..7 (2 slots each)
    int sn = tile0 + sr;
    bool svalid = sn < N_NODES;

    // stage hb (K 0..127)
    if (sp == 0) degb[sr] = svalid ? (float)g_cnt[sn] : 0.f;
#pragma unroll
    for (int q = 0; q < 2; ++q) {
        int slot = sp * 2 + q;
        uint4 v = make_uint4(0, 0, 0, 0);
        if (svalid) v = *(const uint4*)&g_hb[(size_t)sn * HID + slot * 8];
        *(uint4*)&Abuf[sr * 128 + ((slot ^ (sr & 7)) << 3)] = v;
    }
    __syncthreads();

    f32x4 acc0[2], acc1[2];
#pragma unroll
    for (int i = 0; i < 2; ++i) { acc0[i] = (f32x4){0.f,0.f,0.f,0.f}; acc1[i] = (f32x4){0.f,0.f,0.f,0.f}; }
    int r0 = arow, r1 = arow + 16;     // (r0&7)==(r1&7)==(arow&7)
#pragma unroll
    for (int ks = 0; ks < 4; ++ks) {
        int slot = ks * 4 + kgrp;
        bf16x8 a0 = *(const bf16x8*)&Abuf[r0 * 128 + ((slot ^ (arow & 7)) << 3)];
        bf16x8 a1 = *(const bf16x8*)&Abuf[r1 * 128 + ((slot ^ (arow & 7)) << 3)];
#pragma unroll
        for (int ntl = 0; ntl < 2; ++ntl) {
            bf16x8 b = *(const bf16x8*)&w1p[((size_t)(ks * 8 + wave * 2 + ntl) * 64 + lane) * 8];
            acc0[ntl] = __builtin_amdgcn_mfma_f32_16x16x32_bf16(a0, b, acc0[ntl], 0, 0, 0);
            acc1[ntl] = __builtin_amdgcn_mfma_f32_16x16x32_bf16(a1, b, acc1[ntl], 0, 0, 0);
        }
    }
    __syncthreads();

    // stage S (K 128..255) as bf16
#pragma unroll
    for (int q = 0; q < 2; ++q) {
        int slot = sp * 2 + q;
        uint4 v = make_uint4(0, 0, 0, 0);
        if (svalid) {
            const float* spt = &g_S[(size_t)sn * HID + slot * 8];
            float4 f0 = *(const float4*)spt;
            float4 f1 = *((const float4*)spt + 1);
            v.x = f2bf(f0.x) | ((uint32_t)f2bf(f0.y) << 16);
            v.y = f2bf(f0.z) | ((uint32_t)f2bf(f0.w) << 16);
            v.z = f2bf(f1.x) | ((uint32_t)f2bf(f1.y) << 16);
            v.w = f2bf(f1.z) | ((uint32_t)f2bf(f1.w) << 16);
        }
        *(uint4*)&Abuf[sr * 128 + ((slot ^ (sr & 7)) << 3)] = v;
    }
    __syncthreads();

#pragma unroll
    for (int ks = 0; ks < 4; ++ks) {
        int slot = ks * 4 + kgrp;
        bf16x8 a0 = *(const bf16x8*)&Abuf[r0 * 128 + ((slot ^ (arow & 7)) << 3)];
        bf16x8 a1 = *(const bf16x8*)&Abuf[r1 * 128 + ((slot ^ (arow & 7)) << 3)];
#pragma unroll
        for (int ntl = 0; ntl < 2; ++ntl) {
            bf16x8 b = *(const bf16x8*)&w1p[((size_t)((ks + 4) * 8 + wave * 2 + ntl) * 64 + lane) * 8];
            acc0[ntl] = __builtin_amdgcn_mfma_f32_16x16x32_bf16(a0, b, acc0[ntl], 0, 0, 0);
            acc1[ntl] = __builtin_amdgcn_mfma_f32_16x16x32_bf16(a1, b, acc1[ntl], 0, 0, 0);
        }
    }

    // epilogue1: + deg*bc + ub1, relu -> Hbuf
    float dg0[4], dg1[4];
#pragma unroll
    for (int q = 0; q < 4; ++q) {
        dg0[q] = degb[kgrp * 4 + q];
        dg1[q] = degb[16 + kgrp * 4 + q];
    }
#pragma unroll
    for (int ntl = 0; ntl < 2; ++ntl) {
        int col = wave * 32 + ntl * 16 + arow;
        float bv1 = ub1[col], bcv = g_bc[L * 128 + col];
        int slotH = col >> 3, cl = col & 7;
#pragma unroll
        for (int q = 0; q < 4; ++q) {
            int rw0 = kgrp * 4 + q;
            float h0 = fmaxf(acc0[ntl][q] + dg0[q] * bcv + bv1, 0.f);
            Hbuf[rw0 * 128 + ((slotH ^ (rw0 & 7)) << 3) + cl] = f2bf(h0);
            int rw1 = rw0 + 16;
            float h1 = fmaxf(acc1[ntl][q] + dg1[q] * bcv + bv1, 0.f);
            Hbuf[rw1 * 128 + ((slotH ^ (rw1 & 7)) << 3) + cl] = f2bf(h1);
        }
    }
    __syncthreads();

    f32x4 c0[2], c1[2];
#pragma unroll
    for (int i = 0; i < 2; ++i) { c0[i] = (f32x4){0.f,0.f,0.f,0.f}; c1[i] = (f32x4){0.f,0.f,0.f,0.f}; }
#pragma unroll
    for (int ks = 0; ks < 4; ++ks) {
        int slot = ks * 4 + kgrp;
        bf16x8 a0 = *(const bf16x8*)&Hbuf[r0 * 128 + ((slot ^ (arow & 7)) << 3)];
        bf16x8 a1 = *(const bf16x8*)&Hbuf[r1 * 128 + ((slot ^ (arow & 7)) << 3)];
#pragma unroll
        for (int ntl = 0; ntl < 2; ++ntl) {
            bf16x8 b = *(const bf16x8*)&w2p[((size_t)(ks * 8 + wave * 2 + ntl) * 64 + lane) * 8];
            c0[ntl] = __builtin_amdgcn_mfma_f32_16x16x32_bf16(a0, b, c0[ntl], 0, 0, 0);
            c1[ntl] = __builtin_amdgcn_mfma_f32_16x16x32_bf16(a1, b, c1[ntl], 0, 0, 0);
        }
    }

    // + ub2; LN stats (per-wave partial over 32 cols, combine 4 waves via LDS)
    float bv2[2], gm[2], bt[2];
#pragma unroll
    for (int ntl = 0; ntl < 2; ++ntl) {
        int col = wave * 32 + ntl * 16 + arow;
        bv2[ntl] = ub2[col]; gm[ntl] = lng[col]; bt[ntl] = lnb[col];
    }
    float s0[4] = {0,0,0,0}, s1[4] = {0,0,0,0}, q0[4] = {0,0,0,0}, q1[4] = {0,0,0,0};
#pragma unroll
    for (int ntl = 0; ntl < 2; ++ntl)
#pragma unroll
        for (int q = 0; q < 4; ++q) {
            float v0 = c0[ntl][q] + bv2[ntl];
            float v1 = c1[ntl][q] + bv2[ntl];
            c0[ntl][q] = v0; c1[ntl][q] = v1;
            s0[q] += v0; q0[q] += v0 * v0;
            s1[q] += v1; q1[q] += v1 * v1;
        }
#pragma unroll
    for (int m = 1; m < 16; m <<= 1)
#pragma unroll
        for (int q = 0; q < 4; ++q) {
            s0[q] += __shfl_xor(s0[q], m); q0[q] += __shfl_xor(q0[q], m);
            s1[q] += __shfl_xor(s1[q], m); q1[q] += __shfl_xor(q1[q], m);
        }
    if (arow == 0) {
#pragma unroll
        for (int q = 0; q < 4; ++q) {
            int rw0 = kgrp * 4 + q;
            rsums[wave][0][rw0] = s0[q]; rsums[wave][1][rw0] = q0[q];
            rsums[wave][0][rw0 + 16] = s1[q]; rsums[wave][1][rw0 + 16] = q1[q];
        }
    }
    __syncthreads();

    float mean0[4], rstd0[4], mean1[4], rstd1[4];
#pragma unroll
    for (int q = 0; q < 4; ++q) {
        int rw0 = kgrp * 4 + q;
        float sm = rsums[0][0][rw0] + rsums[1][0][rw0] + rsums[2][0][rw0] + rsums[3][0][rw0];
        float sq = rsums[0][1][rw0] + rsums[1][1][rw0] + rsums[2][1][rw0] + rsums[3][1][rw0];
        mean0[q] = sm * (1.f / HID);
        rstd0[q] = rsqrtf(sq * (1.f / HID) - mean0[q] * mean0[q] + 1e-5f);
        int rw1 = rw0 + 16;
        sm = rsums[0][0][rw1] + rsums[1][0][rw1] + rsums[2][0][rw1] + rsums[3][0][rw1];
        sq = rsums[0][1][rw1] + rsums[1][1][rw1] + rsums[2][1][rw1] + rsums[3][1][rw1];
        mean1[q] = sm * (1.f / HID);
        rstd1[q] = rsqrtf(sq * (1.f / HID) - mean1[q] * mean1[q] + 1e-5f);
    }

    // LN apply + residual into regs; hn bf16 -> Abuf (swizzled)
#pragma unroll
    for (int ntl = 0; ntl < 2; ++ntl) {
        int col = wave * 32 + ntl * 16 + arow;
        int slotA = col >> 3, clA = col & 7;
#pragma unroll
        for (int q = 0; q < 4; ++q) {
            int rw0 = kgrp * 4 + q;
            int row0 = tile0 + rw0;
            float u0 = fmaxf((c0[ntl][q] - mean0[q]) * rstd0[q] * gm[ntl] + bt[ntl], 0.f);
            float hr0 = (!first_layer && row0 < N_NODES) ? g_h[(size_t)row0 * HID + col] : 0.f;
            float hn0 = first_layer ? u0 : (hr0 + u0);
            c0[ntl][q] = hn0;
            Abuf[rw0 * 128 + ((slotA ^ (rw0 & 7)) << 3) + clA] = f2bf(hn0);
            int rw1 = rw0 + 16;
            int row1 = row0 + 16;
            float u1 = fmaxf((c1[ntl][q] - mean1[q]) * rstd1[q] * gm[ntl] + bt[ntl], 0.f);
            float hr1 = (!first_layer && row1 < N_NODES) ? g_h[(size_t)row1 * HID + col] : 0.f;
            float hn1 = first_layer ? u1 : (hr1 + u1);
            c1[ntl][q] = hn1;
            Abuf[rw1 * 128 + ((slotA ^ (rw1 & 7)) << 3) + clA] = f2bf(hn1);
        }
    }
    __syncthreads();   // Abuf(hn bf16) complete; Hbuf free

    // f32 h copy-out via Hbuf-as-FB (16 rows x 128 f32 = 8KB), two passes
    float* FB = (float*)Hbuf;
    {
        // pass 0: rows 0..15 (c0)
#pragma unroll
        for (int ntl = 0; ntl < 2; ++ntl) {
            int col = wave * 32 + ntl * 16 + arow;
#pragma unroll
            for (int q = 0; q < 4; ++q) FB[(kgrp * 4 + q) * 128 + col] = c0[ntl][q];
        }
        __syncthreads();
#pragma unroll
        for (int i = 0; i < 2; ++i) {
            int pos = t + i * 256;          // 0..511 float4 slots (16 rows x 32)
            int row = pos >> 5, cc = pos & 31;
            int n = tile0 + row;
            if (n < N_NODES)
                *(float4*)&g_h[(size_t)n * HID + cc * 4] = *(const float4*)&FB[row * 128 + cc * 4];
        }
        __syncthreads();
        // pass 1: rows 16..31 (c1)
#pragma unroll
        for (int ntl = 0; ntl < 2; ++ntl) {
            int col = wave * 32 + ntl * 16 + arow;
#pragma unroll
            for (int q = 0; q < 4; ++q) FB[(kgrp * 4 + q) * 128 + col] = c1[ntl][q];
        }
        __syncthreads();
#pragma unroll
        for (int i = 0; i < 2; ++i) {
            int pos = t + i * 256;
            int row = pos >> 5, cc = pos & 31;
            int n = tile0 + 16 + row;
            if (n < N_NODES)
                *(float4*)&g_h[(size_t)n * HID + cc * 4] = *(const float4*)&FB[row * 128 + cc * 4];
        }
        __syncthreads();
    }

    if (Lpq < 0) return;   // last layer: nothing consumes hb or PQ

    // hb copy-out from Abuf (coalesced): 32 rows x 16 slots = 512, 2/thread
#pragma unroll
    for (int i = 0; i < 2; ++i) {
        int pos = t + i * 256;
        int row = pos >> 4, s = pos & 15;
        int n = tile0 + row;
        if (n < N_NODES)
            *(uint4*)&g_hb[(size_t)n * HID + s * 8] =
                *(const uint4*)&Abuf[row * 128 + ((s ^ (row & 7)) << 3)];
    }

    // GEMM3: PQ = hn @ pqw[Lpq], N=256 in two 128-col halves via Hbuf
    const unsigned short* wp = g_pqw + (size_t)Lpq * 4 * 16 * 64 * 8;
#pragma unroll
    for (int h = 0; h < 2; ++h) {
        bf16x8 w3[4][2];
#pragma unroll
        for (int ks = 0; ks < 4; ++ks)
#pragma unroll
            for (int j = 0; j < 2; ++j) {
                int nt = h * 8 + wave * 2 + j;
                w3[ks][j] = *(const bf16x8*)&wp[((size_t)(ks * 16 + nt) * 64 + lane) * 8];
            }
        f32x4 a3[2][2];   // [row frag 0/1][j]
#pragma unroll
        for (int rf = 0; rf < 2; ++rf)
#pragma unroll
            for (int j = 0; j < 2; ++j) a3[rf][j] = (f32x4){0.f, 0.f, 0.f, 0.f};
#pragma unroll
        for (int ks = 0; ks < 4; ++ks) {
            int slot = ks * 4 + kgrp;
            bf16x8 a0 = *(const bf16x8*)&Abuf[r0 * 128 + ((slot ^ (arow & 7)) << 3)];
            bf16x8 a1 = *(const bf16x8*)&Abuf[r1 * 128 + ((slot ^ (arow & 7)) << 3)];
#pragma unroll
            for (int j = 0; j < 2; ++j) {
                a3[0][j] = __builtin_amdgcn_mfma_f32_16x16x32_bf16(a0, w3[ks][j], a3[0][j], 0, 0, 0);
                a3[1][j] = __builtin_amdgcn_mfma_f32_16x16x32_bf16(a1, w3[ks][j], a3[1][j], 0, 0, 0);
            }
        }
        __syncthreads();   // prior Hbuf readers done
#pragma unroll
        for (int j = 0; j < 2; ++j) {
            int cl2 = (wave * 2 + j) * 16 + arow;   // 0..127 within half
            int slotP = cl2 >> 3, clP = cl2 & 7;
#pragma unroll
            for (int q = 0; q < 4; ++q) {
                int row = kgrp * 4 + q;
                Hbuf[row * 128 + ((slotP ^ (row & 7)) << 3) + clP] = f2bf(a3[0][j][q]);
                int row2 = row + 16;
                Hbuf[row2 * 128 + ((slotP ^ (row2 & 7)) << 3) + clP] = f2bf(a3[1][j][q]);
            }
        }
        __syncthreads();
#pragma unroll
        for (int i = 0; i < 2; ++i) {
            int u = t + i * 256;
            int row = u >> 4, s = u & 15;
            int n2 = tile0 + row;
            if (n2 < N_NODES)
                *(uint4*)&g_PQ[(size_t)n2 * 256 + h * 128 + s * 8] =
                    *(const uint4*)&Hbuf[row * 128 + ((s ^ (row & 7)) << 3)];
        }
        __syncthreads();
    }
}

// ---------------- global mean pool: 8 blocks per graph, atomic partials ----------------
__global__ __launch_bounds__(256, 8)
void pool_k(const int* __restrict__ batch) {
    __shared__ int se[2];
    __shared__ float part[2][128];
    int b = blockIdx.x;
    int g = b >> 3, sub = b & 7;
    int t = threadIdx.x;
    if (t == 0) {
        int lo = 0, hi = N_NODES;
        while (lo < hi) { int m = (lo + hi) >> 1; if (batch[m] < g) lo = m + 1; else hi = m; }
        se[0] = lo;
        hi = N_NODES;
        while (lo < hi) { int m = (lo + hi) >> 1; if (batch[m] < g + 1) lo = m + 1; else hi = m; }
        se[1] = lo;
    }
    __syncthreads();
    int s = se[0], e = se[1];
    int c = t & 127, half = t >> 7;
    float acc = 0.f;
    for (int n = s + sub * 2 + half; n < e; n += 16) acc += g_h[(size_t)n * HID + c];
    part[half][c] = acc;
    __syncthreads();
    if (t < 128) {
        float v = part[0][t] + part[1][t];
        atomicAdd(&g_pooled[g * HID + t], v);
    }
}

// ---------------- readout MLP (divides pooled sums by graph size) ----------------
__global__ void readout_k(const int* __restrict__ batch,
                          const float* __restrict__ w1, const float* __restrict__ b1,
                          const float* __restrict__ w2, const float* __restrict__ b2,
                          const float* __restrict__ w3, const float* __restrict__ b3,
                          float* __restrict__ out) {
    __shared__ float p[128], o1[128], o2[64];
    __shared__ int se[2];
    int g = blockIdx.x, t = threadIdx.x;
    if (t == 0) {
        int lo = 0, hi = N_NODES;
        while (lo < hi) { int m = (lo + hi) >> 1; if (batch[m] < g) lo = m + 1; else hi = m; }
        se[0] = lo;
        hi = N_NODES;
        while (lo < hi) { int m = (lo + hi) >> 1; if (batch[m] < g + 1) lo = m + 1; else hi = m; }
        se[1] = lo;
    }
    __syncthreads();
    float cntf = fmaxf((float)(se[1] - se[0]), 1.f);
    p[t] = g_pooled[g * HID + t] / cntf;
    __syncthreads();
    float a = b1[t];
    for (int k = 0; k < 128; ++k) a += p[k] * w1[k * 128 + t];
    o1[t] = fmaxf(a, 0.f);
    __syncthreads();
    if (t < 64) {
        float a2 = b2[t];
        for (int k = 0; k < 128; ++k) a2 += o1[k] * w2[k * 64 + t];
        o2[t] = fmaxf(a2, 0.f);
    }
    __syncthreads();
    if (t == 0) {
        float a3 = b3[0];
        for (int k = 0; k < 64; ++k) a3 += o2[k] * w3[k];
        out[g] = a3;
    }
}

extern "C" void kernel_launch(void* const* d_in, const int* in_sizes, int n_in,
                              void* d_out, int out_size, void* d_ws, size_t ws_size,
                              hipStream_t stream) {
    const float* x     = (const float*)d_in[0];
    const int*   ei    = (const int*)d_in[1];
    const float* pos   = (const float*)d_in[3];
    const int*   batch = (const int*)d_in[4];
    const float* enc_w = (const float*)d_in[5];
    const float* enc_b = (const float*)d_in[6];
    const float* msg_w1 = (const float*)d_in[9];
    const float* msg_b1 = (const float*)d_in[10];
    const float* msg_w2 = (const float*)d_in[11];
    const float* msg_b2 = (const float*)d_in[12];
    const float* upd_w1 = (const float*)d_in[13];
    const float* upd_b1 = (const float*)d_in[14];
    const float* upd_w2 = (const float*)d_in[15];
    const float* upd_b2 = (const float*)d_in[16];
    const float* ln_g   = (const float*)d_in[17];
    const float* ln_b   = (const float*)d_in[18];
    const float* mw1 = (const float*)d_in[19];
    const float* mb1 = (const float*)d_in[20];
    const float* mw2 = (const float*)d_in[21];
    const float* mb2 = (const float*)d_in[22];
    const float* mw3 = (const float*)d_in[23];
    const float* mb3 = (const float*)d_in[24];
    float* out = (float*)d_out;
    (void)d_ws; (void)ws_size; (void)in_sizes; (void)n_in; (void)out_size;

    // weight preprocessing
    pack_pqw_k<<<NLAYERS * 4 * 16, 64, 0, stream>>>(msg_w1);
    wc_k<<<NLAYERS * 128, 128, 0, stream>>>(msg_w2, upd_w1);
    bc_k<<<NLAYERS, 128, 0, stream>>>(msg_b2, upd_w1);
    pack_u1_k<<<NLAYERS * 8 * 8, 64, 0, stream>>>(upd_w1);
    pack_w2_k<<<NLAYERS * 4 * 8, 64, 0, stream>>>(upd_w2);

    encode_k<<<N_NODES / 2, 256, 0, stream>>>(x, enc_w, enc_b);

    clear_cnt_k<<<(N_NODES + 255) / 256, 256, 0, stream>>>();
    hist_k<<<(N_EDGES + 255) / 256, 256, 0, stream>>>(ei);
    int nb = (N_NODES + 511) / 512;
    scanA_k<<<nb, 512, 0, stream>>>();
    scanB_k<<<1, 64, 0, stream>>>(nb);
    scanC_k<<<nb, 512, 0, stream>>>();
    scatter_k<<<(N_EDGES + 255) / 256, 256, 0, stream>>>(ei, pos);

    pq_k<<<NTILES, 256, 0, stream>>>(0);
    clear_pooled_k<<<32, 256, 0, stream>>>();
    for (int L = 0; L < NLAYERS; ++L) {
        edge_relu_k<<<EBLOCKS, 256, 0, stream>>>(
            msg_w1 + (size_t)L * 257 * HID + 256 * HID, msg_b1 + L * HID);
        upd_k<<<NT32, 256, 0, stream>>>(
            upd_b1 + L * HID, upd_b2 + L * HID, ln_g + L * HID, ln_b + L * HID,
            L, L == 0 ? 1 : 0, L < NLAYERS - 1 ? L + 1 : -1);
    }

    pool_k<<<NGRAPHS * 8, 256, 0, stream>>>(batch);
    readout_k<<<NGRAPHS, 128, 0, stream>>>(batch, mw1, mb1, mw2, mb2, mw3, mb3, out);
}

// Round 14
// 554.082 us; speedup vs baseline: 1.3512x; 1.3512x over previous
//
#include <hip/hip_runtime.h>
#include <hip/hip_bf16.h>
#include <cstdint>

#define N_NODES 50000
#define N_EDGES 500000
#define HID 128
#define NLAYERS 4
#define NGRAPHS 64
#define NTILES ((N_NODES + 63) / 64)    // 782
#define NPW 4                            // nodes per wave in edge kernel
#define EBLOCKS ((N_NODES + NPW * 4 - 1) / (NPW * 4))   // 3125

typedef float f32x4 __attribute__((ext_vector_type(4)));
typedef __bf16 bf16x8 __attribute__((ext_vector_type(8)));

// ---- scratch in device globals (module-load allocated; d_ws unused) ----
__device__ float          g_h[(size_t)N_NODES * HID];
__device__ unsigned short g_hb[(size_t)N_NODES * HID];
__device__ float          g_S[(size_t)N_NODES * HID];
__device__ unsigned short g_PQ[(size_t)N_NODES * 256];
__device__ int2           g_edge[N_EDGES];              // {src, dist bits}
__device__ int            g_cnt[N_NODES];
__device__ int            g_cursor[N_NODES];
__device__ int            g_bsum[1024];
__device__ unsigned short g_pqw[NLAYERS * 4 * 16 * 64 * 8];
__device__ float          g_wc[NLAYERS * 128 * 128];
__device__ float          g_bc[NLAYERS * 128];
__device__ unsigned short g_uw1p[NLAYERS * 8 * 8 * 64 * 8];
__device__ unsigned short g_uw2p[NLAYERS * 4 * 8 * 64 * 8];
__device__ float          g_pooled[NGRAPHS * HID];

__device__ __forceinline__ unsigned short f2bf(float f) {
    uint32_t u = __builtin_bit_cast(uint32_t, f);
    uint32_t r = (u + 0x7fffu + ((u >> 16) & 1u)) >> 16;
    return (unsigned short)r;
}
__device__ __forceinline__ float bf2f(unsigned short u) {
    return __builtin_bit_cast(float, (uint32_t)u << 16);
}

// ---------------- clears ----------------
__global__ void clear_cnt_k() {
    int i = blockIdx.x * 256 + threadIdx.x;
    if (i < N_NODES) g_cnt[i] = 0;
}
__global__ void clear_pooled_k() {
    int i = blockIdx.x * 256 + threadIdx.x;
    if (i < NGRAPHS * HID) g_pooled[i] = 0.f;
}

// ---------------- weight preprocessing ----------------
__global__ void pack_pqw_k(const float* __restrict__ w1) {
    int lane = threadIdx.x;
    int bid = blockIdx.x;                  // L*64 + ks*16 + nt
    int nt = bid & 15, ks = (bid >> 4) & 3, L = bid >> 6;
    const float* w = w1 + (size_t)L * 257 * HID;
    int kb = ks * 32 + (lane >> 4) * 8;
    int n = nt * 16 + (lane & 15);
    unsigned short tmp[8];
#pragma unroll
    for (int j = 0; j < 8; ++j) {
        int k = kb + j;
        float v = (n < 128) ? w[(size_t)k * HID + n] : w[(size_t)(128 + k) * HID + (n - 128)];
        tmp[j] = f2bf(v);
    }
    uint4 o = make_uint4(tmp[0] | ((uint32_t)tmp[1] << 16), tmp[2] | ((uint32_t)tmp[3] << 16),
                         tmp[4] | ((uint32_t)tmp[5] << 16), tmp[6] | ((uint32_t)tmp[7] << 16));
    *(uint4*)&g_pqw[(((size_t)(L * 4 + ks) * 16 + nt) * 64 + lane) * 8] = o;
}

__global__ void wc_k(const float* __restrict__ mw2, const float* __restrict__ uw1) {
    __shared__ float row[128];
    int L = blockIdx.x >> 7, k = blockIdx.x & 127, j = threadIdx.x;
    row[j] = mw2[(size_t)L * 128 * 128 + k * 128 + j];
    __syncthreads();
    const float* u1b = uw1 + (size_t)L * 256 * 128 + 128 * 128;
    float s = 0.f;
    for (int i = 0; i < 128; ++i) s += row[i] * u1b[i * 128 + j];
    g_wc[(size_t)L * 128 * 128 + k * 128 + j] = s;
}
__global__ void bc_k(const float* __restrict__ mb2, const float* __restrict__ uw1) {
    int L = blockIdx.x, j = threadIdx.x;
    const float* u1b = uw1 + (size_t)L * 256 * 128 + 128 * 128;
    const float* b2 = mb2 + L * 128;
    float s = 0.f;
    for (int i = 0; i < 128; ++i) s += b2[i] * u1b[i * 128 + j];
    g_bc[L * 128 + j] = s;
}

__global__ void pack_u1_k(const float* __restrict__ uw1) {
    int lane = threadIdx.x;
    int bid = blockIdx.x;                  // L*64 + ks*8 + nt
    int nt = bid & 7, ks = (bid >> 3) & 7, L = bid >> 6;
    int kb = ks * 32 + (lane >> 4) * 8;
    int n = nt * 16 + (lane & 15);
    unsigned short tmp[8];
#pragma unroll
    for (int j = 0; j < 8; ++j) {
        int k = kb + j;
        float v = (k < 128) ? uw1[(size_t)L * 256 * 128 + (size_t)k * 128 + n]
                            : g_wc[(size_t)L * 128 * 128 + (size_t)(k - 128) * 128 + n];
        tmp[j] = f2bf(v);
    }
    uint4 o = make_uint4(tmp[0] | ((uint32_t)tmp[1] << 16), tmp[2] | ((uint32_t)tmp[3] << 16),
                         tmp[4] | ((uint32_t)tmp[5] << 16), tmp[6] | ((uint32_t)tmp[7] << 16));
    *(uint4*)&g_uw1p[(((size_t)(L * 8 + ks) * 8 + nt) * 64 + lane) * 8] = o;
}

__global__ void pack_w2_k(const float* __restrict__ uw2) {
    int lane = threadIdx.x;
    int bid = blockIdx.x;                  // L*32 + ks*8 + nt
    int nt = bid & 7, ks = (bid >> 3) & 3, L = bid >> 5;
    int kb = ks * 32 + (lane >> 4) * 8;
    int n = nt * 16 + (lane & 15);
    unsigned short tmp[8];
#pragma unroll
    for (int j = 0; j < 8; ++j)
        tmp[j] = f2bf(uw2[(size_t)L * 128 * 128 + (size_t)(kb + j) * 128 + n]);
    uint4 o = make_uint4(tmp[0] | ((uint32_t)tmp[1] << 16), tmp[2] | ((uint32_t)tmp[3] << 16),
                         tmp[4] | ((uint32_t)tmp[5] << 16), tmp[6] | ((uint32_t)tmp[7] << 16));
    *(uint4*)&g_uw2p[(((size_t)(L * 4 + ks) * 8 + nt) * 64 + lane) * 8] = o;
}

// ---------------- node encoder ----------------
__global__ void encode_k(const float* __restrict__ x, const float* __restrict__ w,
                         const float* __restrict__ b) {
    __shared__ float xl[2][15];
    int t = threadIdx.x;
    int half = t >> 7;
    int node = blockIdx.x * 2 + half;
    int c = t & 127;
    if (c < 15) xl[half][c] = x[(size_t)node * 15 + c];
    __syncthreads();
    float acc = b[c];
#pragma unroll
    for (int k = 0; k < 15; ++k) acc += xl[half][k] * w[k * HID + c];
    g_h[(size_t)node * HID + c] = acc;
    g_hb[(size_t)node * HID + c] = f2bf(acc);
}

// ---------------- counting sort of edges by dst ----------------
__global__ void hist_k(const int* __restrict__ ei) {
    int e = blockIdx.x * 256 + threadIdx.x;
    if (e < N_EDGES) atomicAdd(&g_cnt[ei[N_EDGES + e]], 1);
}
__global__ void scanA_k() {
    __shared__ int s[512];
    int t = threadIdx.x;
    int i = blockIdx.x * 512 + t;
    s[t] = (i < N_NODES) ? g_cnt[i] : 0;
    __syncthreads();
    for (int d = 256; d > 0; d >>= 1) {
        if (t < d) s[t] += s[t + d];
        __syncthreads();
    }
    if (t == 0) g_bsum[blockIdx.x] = s[0];
}
__global__ void scanB_k(int nb) {
    if (threadIdx.x == 0) {
        int acc = 0;
        for (int i = 0; i < nb; ++i) { int v = g_bsum[i]; g_bsum[i] = acc; acc += v; }
    }
}
__global__ void scanC_k() {
    __shared__ int s[512];
    int t = threadIdx.x;
    int i = blockIdx.x * 512 + t;
    int v = (i < N_NODES) ? g_cnt[i] : 0;
    s[t] = v;
    __syncthreads();
    for (int d = 1; d < 512; d <<= 1) {
        int add = (t >= d) ? s[t - d] : 0;
        __syncthreads();
        s[t] += add;
        __syncthreads();
    }
    if (i < N_NODES) g_cursor[i] = g_bsum[blockIdx.x] + s[t] - v;
}
__global__ void scatter_k(const int* __restrict__ ei, const float* __restrict__ pos) {
    int e = blockIdx.x * 256 + threadIdx.x;
    if (e >= N_EDGES) return;
    int s = ei[e];
    int d = ei[N_EDGES + e];
    float dx = pos[d * 3 + 0] - pos[s * 3 + 0];
    float dy = pos[d * 3 + 1] - pos[s * 3 + 1];
    float dz = pos[d * 3 + 2] - pos[s * 3 + 2];
    float dist = sqrtf(dx * dx + dy * dy + dz * dz);
    int p = atomicAdd(&g_cursor[d], 1);
    g_edge[p] = make_int2(s, __builtin_bit_cast(int, dist));   // one 8B store
}
// after scatter_k: g_cursor[n] == end offset; start = end - g_cnt[n].

// ---------------- PQ = hb @ [Wd|Ws]  (standalone, only for layer 0) ----------------
__global__ __launch_bounds__(256, 2)
void pq_k(int L) {
    __shared__ unsigned short Abuf[64 * 128];
    __shared__ unsigned short Obuf[64 * 264];
    const unsigned short* wp = g_pqw + (size_t)L * 4 * 16 * 64 * 8;
    int t = threadIdx.x, wave = t >> 6, lane = t & 63;
    int arow = lane & 15, kgrp = lane >> 4;
    int tile0 = blockIdx.x * 64;

    {
        int r = t >> 2, p = t & 3;
        int n = tile0 + r;
        bool valid = n < N_NODES;
#pragma unroll
        for (int q = 0; q < 4; ++q) {
            int slot = p * 4 + q;
            uint4 v = make_uint4(0, 0, 0, 0);
            if (valid) v = *(const uint4*)&g_hb[(size_t)n * HID + slot * 8];
            *(uint4*)&Abuf[r * 128 + ((slot ^ (r & 7)) << 3)] = v;
        }
    }
    __syncthreads();

    bf16x8 wv[4][4];
#pragma unroll
    for (int ks = 0; ks < 4; ++ks)
#pragma unroll
        for (int ntl = 0; ntl < 4; ++ntl)
            wv[ks][ntl] = *(const bf16x8*)&wp[((size_t)(ks * 16 + wave * 4 + ntl) * 64 + lane) * 8];

    f32x4 acc[4][4];
#pragma unroll
    for (int rf = 0; rf < 4; ++rf)
#pragma unroll
        for (int ntl = 0; ntl < 4; ++ntl) acc[rf][ntl] = (f32x4){0.f, 0.f, 0.f, 0.f};
#pragma unroll
    for (int ks = 0; ks < 4; ++ks) {
        int slot = ks * 4 + kgrp;
#pragma unroll
        for (int rf = 0; rf < 4; ++rf) {
            int row = rf * 16 + arow;
            bf16x8 a = *(const bf16x8*)&Abuf[row * 128 + ((slot ^ (row & 7)) << 3)];
#pragma unroll
            for (int ntl = 0; ntl < 4; ++ntl)
                acc[rf][ntl] = __builtin_amdgcn_mfma_f32_16x16x32_bf16(a, wv[ks][ntl], acc[rf][ntl], 0, 0, 0);
        }
    }
#pragma unroll
    for (int rf = 0; rf < 4; ++rf)
#pragma unroll
        for (int ntl = 0; ntl < 4; ++ntl) {
            int col = wave * 64 + ntl * 16 + arow;
#pragma unroll
            for (int q = 0; q < 4; ++q) {
                int row = rf * 16 + kgrp * 4 + q;
                Obuf[row * 264 + col] = f2bf(acc[rf][ntl][q]);
            }
        }
    __syncthreads();
#pragma unroll
    for (int i = 0; i < 8; ++i) {
        int k = t + i * 256;
        int row = k >> 5, cc = k & 31;
        int n = tile0 + row;
        if (n < N_NODES)
            *(uint4*)&g_PQ[(size_t)n * 256 + cc * 8] = *(const uint4*)&Obuf[row * 264 + cc * 8];
    }
}

// ---------------- edge kernel: S[n] = sum_e relu(P[n]+Q[src]+dist*wl+b1) ----------------
__global__ __launch_bounds__(256, 8)
void edge_relu_k(const float* __restrict__ w1last, const float* __restrict__ b1) {
    int t = threadIdx.x, wave = t >> 6, lane = t & 63;
    int c2 = lane * 2;
    float wl0 = w1last[c2], wl1 = w1last[c2 + 1];
    float bb0 = b1[c2], bb1 = b1[c2 + 1];

    int gw = blockIdx.x * 4 + wave;
    int n0 = gw * NPW;
    int n1 = n0 + NPW < N_NODES ? n0 + NPW : N_NODES;

    for (int n = n0; n < n1; ++n) {
        int end = g_cursor[n];
        int cnt = g_cnt[n];
        int beg = end - cnt;
        uint32_t pv = *(const uint32_t*)&g_PQ[(size_t)n * 256 + c2];
        float pb0 = bf2f((unsigned short)(pv & 0xffff)) + bb0;
        float pb1 = bf2f((unsigned short)(pv >> 16)) + bb1;
        float acc0 = 0.f, acc1 = 0.f;

        for (int cb = beg; cb < end; cb += 64) {
            int mye = cb + lane;
            bool v = mye < end;
            int2 ed = v ? g_edge[mye] : make_int2(0, 0);
            int msrc = ed.x;
            float mdist = __builtin_bit_cast(float, ed.y);
            int lim = end - cb < 64 ? end - cb : 64;
            int full = lim & ~7;
            for (int b = 0; b < full; b += 8) {
                uint32_t qv[8];
#pragma unroll
                for (int j = 0; j < 8; ++j) {
                    int s = __shfl(msrc, b + j);
                    qv[j] = *(const uint32_t*)&g_PQ[(size_t)s * 256 + 128 + c2];
                }
#pragma unroll
                for (int j = 0; j < 8; ++j) {
                    float dist = __shfl(mdist, b + j);
                    acc0 += fmaxf(fmaf(dist, wl0, pb0 + bf2f((unsigned short)(qv[j] & 0xffff))), 0.f);
                    acc1 += fmaxf(fmaf(dist, wl1, pb1 + bf2f((unsigned short)(qv[j] >> 16))), 0.f);
                }
            }
            for (int j = full; j < lim; ++j) {
                int s = __shfl(msrc, j);
                float dist = __shfl(mdist, j);
                uint32_t qv = *(const uint32_t*)&g_PQ[(size_t)s * 256 + 128 + c2];
                acc0 += fmaxf(fmaf(dist, wl0, pb0 + bf2f((unsigned short)(qv & 0xffff))), 0.f);
                acc1 += fmaxf(fmaf(dist, wl1, pb1 + bf2f((unsigned short)(qv >> 16))), 0.f);
            }
        }
        *(float2*)&g_S[(size_t)n * HID + c2] = make_float2(acc0, acc1);
    }
}

// ---------------- fused node update + PQ for next layer (64-row tiles) ----------------
// Round-12 known-good configuration: 34.3KB LDS, launch_bounds(256,4).
__global__ __launch_bounds__(256, 4)
void upd_k(const float* __restrict__ ub1, const float* __restrict__ ub2,
           const float* __restrict__ lng, const float* __restrict__ lnb,
           int L, int first_layer, int Lpq) {
    __shared__ unsigned short Abuf[64 * 128];   // 16KB: hb -> S -> hn(bf16)
    __shared__ unsigned short Hbuf[64 * 128];   // 16KB: hidden -> f32 h halves -> PQ halves
    __shared__ float rsums[2][2][64];
    __shared__ float degb[64];
    const unsigned short* w1p = g_uw1p + (size_t)L * 8 * 8 * 64 * 8;
    const unsigned short* w2p = g_uw2p + (size_t)L * 4 * 8 * 64 * 8;
    int t = threadIdx.x, wave = t >> 6, lane = t & 63;
    int wr = wave >> 1, wc = wave & 1;
    int arow = lane & 15, kgrp = lane >> 4;
    int tile0 = blockIdx.x * 64;

    int sr = t >> 2, sp = t & 3;
    int sn = tile0 + sr;
    bool svalid = sn < N_NODES;

    // stage hb (K 0..127)
    if (sp == 0) degb[sr] = svalid ? (float)g_cnt[sn] : 0.f;
#pragma unroll
    for (int q = 0; q < 4; ++q) {
        int slot = sp * 4 + q;
        uint4 v = make_uint4(0, 0, 0, 0);
        if (svalid) v = *(const uint4*)&g_hb[(size_t)sn * HID + slot * 8];
        *(uint4*)&Abuf[sr * 128 + ((slot ^ (sr & 7)) << 3)] = v;
    }
    __syncthreads();

    f32x4 acc0[4], acc1[4];
#pragma unroll
    for (int i = 0; i < 4; ++i) { acc0[i] = (f32x4){0.f,0.f,0.f,0.f}; acc1[i] = (f32x4){0.f,0.f,0.f,0.f}; }
    int r0 = wr * 32 + arow, r1 = r0 + 16;
#pragma unroll
    for (int ks = 0; ks < 4; ++ks) {
        int slot = ks * 4 + kgrp;
        bf16x8 a0 = *(const bf16x8*)&Abuf[r0 * 128 + ((slot ^ (arow & 7)) << 3)];
        bf16x8 a1 = *(const bf16x8*)&Abuf[r1 * 128 + ((slot ^ (arow & 7)) << 3)];
#pragma unroll
        for (int ntl = 0; ntl < 4; ++ntl) {
            bf16x8 b = *(const bf16x8*)&w1p[((size_t)(ks * 8 + wc * 4 + ntl) * 64 + lane) * 8];
            acc0[ntl] = __builtin_amdgcn_mfma_f32_16x16x32_bf16(a0, b, acc0[ntl], 0, 0, 0);
            acc1[ntl] = __builtin_amdgcn_mfma_f32_16x16x32_bf16(a1, b, acc1[ntl], 0, 0, 0);
        }
    }
    __syncthreads();

    // stage S (K 128..255) as bf16
#pragma unroll
    for (int q = 0; q < 4; ++q) {
        int slot = sp * 4 + q;
        uint4 v = make_uint4(0, 0, 0, 0);
        if (svalid) {
            const float* spt = &g_S[(size_t)sn * HID + slot * 8];
            float4 f0 = *(const float4*)spt;
            float4 f1 = *((const float4*)spt + 1);
            v.x = f2bf(f0.x) | ((uint32_t)f2bf(f0.y) << 16);
            v.y = f2bf(f0.z) | ((uint32_t)f2bf(f0.w) << 16);
            v.z = f2bf(f1.x) | ((uint32_t)f2bf(f1.y) << 16);
            v.w = f2bf(f1.z) | ((uint32_t)f2bf(f1.w) << 16);
        }
        *(uint4*)&Abuf[sr * 128 + ((slot ^ (sr & 7)) << 3)] = v;
    }
    __syncthreads();

#pragma unroll
    for (int ks = 0; ks < 4; ++ks) {
        int slot = ks * 4 + kgrp;
        bf16x8 a0 = *(const bf16x8*)&Abuf[r0 * 128 + ((slot ^ (arow & 7)) << 3)];
        bf16x8 a1 = *(const bf16x8*)&Abuf[r1 * 128 + ((slot ^ (arow & 7)) << 3)];
#pragma unroll
        for (int ntl = 0; ntl < 4; ++ntl) {
            bf16x8 b = *(const bf16x8*)&w1p[((size_t)((ks + 4) * 8 + wc * 4 + ntl) * 64 + lane) * 8];
            acc0[ntl] = __builtin_amdgcn_mfma_f32_16x16x32_bf16(a0, b, acc0[ntl], 0, 0, 0);
            acc1[ntl] = __builtin_amdgcn_mfma_f32_16x16x32_bf16(a1, b, acc1[ntl], 0, 0, 0);
        }
    }

    // epilogue1: + deg*bc + ub1, relu -> Hbuf
    float dg0[4], dg1[4];
#pragma unroll
    for (int q = 0; q < 4; ++q) {
        dg0[q] = degb[wr * 32 + kgrp * 4 + q];
        dg1[q] = degb[wr * 32 + 16 + kgrp * 4 + q];
    }
#pragma unroll
    for (int ntl = 0; ntl < 4; ++ntl) {
        int col = wc * 64 + ntl * 16 + arow;
        float bv1 = ub1[col], bcv = g_bc[L * 128 + col];
        int slotH = col >> 3, cl = col & 7;
#pragma unroll
        for (int q = 0; q < 4; ++q) {
            int rw0 = wr * 32 + kgrp * 4 + q;
            float h0 = fmaxf(acc0[ntl][q] + dg0[q] * bcv + bv1, 0.f);
            Hbuf[rw0 * 128 + ((slotH ^ (rw0 & 7)) << 3) + cl] = f2bf(h0);
            int rw1 = rw0 + 16;
            float h1 = fmaxf(acc1[ntl][q] + dg1[q] * bcv + bv1, 0.f);
            Hbuf[rw1 * 128 + ((slotH ^ (rw1 & 7)) << 3) + cl] = f2bf(h1);
        }
    }
    __syncthreads();

    f32x4 c0[4], c1[4];
#pragma unroll
    for (int i = 0; i < 4; ++i) { c0[i] = (f32x4){0.f,0.f,0.f,0.f}; c1[i] = (f32x4){0.f,0.f,0.f,0.f}; }
#pragma unroll
    for (int ks = 0; ks < 4; ++ks) {
        int slot = ks * 4 + kgrp;
        bf16x8 a0 = *(const bf16x8*)&Hbuf[r0 * 128 + ((slot ^ (arow & 7)) << 3)];
        bf16x8 a1 = *(const bf16x8*)&Hbuf[r1 * 128 + ((slot ^ (arow & 7)) << 3)];
#pragma unroll
        for (int ntl = 0; ntl < 4; ++ntl) {
            bf16x8 b = *(const bf16x8*)&w2p[((size_t)(ks * 8 + wc * 4 + ntl) * 64 + lane) * 8];
            c0[ntl] = __builtin_amdgcn_mfma_f32_16x16x32_bf16(a0, b, c0[ntl], 0, 0, 0);
            c1[ntl] = __builtin_amdgcn_mfma_f32_16x16x32_bf16(a1, b, c1[ntl], 0, 0, 0);
        }
    }

    // + ub2; LN stats
    float bv2[4], gm[4], bt[4];
#pragma unroll
    for (int ntl = 0; ntl < 4; ++ntl) {
        int col = wc * 64 + ntl * 16 + arow;
        bv2[ntl] = ub2[col]; gm[ntl] = lng[col]; bt[ntl] = lnb[col];
    }
    float s0[4] = {0,0,0,0}, s1[4] = {0,0,0,0}, q0[4] = {0,0,0,0}, q1[4] = {0,0,0,0};
#pragma unroll
    for (int ntl = 0; ntl < 4; ++ntl)
#pragma unroll
        for (int q = 0; q < 4; ++q) {
            float v0 = c0[ntl][q] + bv2[ntl];
            float v1 = c1[ntl][q] + bv2[ntl];
            c0[ntl][q] = v0; c1[ntl][q] = v1;
            s0[q] += v0; q0[q] += v0 * v0;
            s1[q] += v1; q1[q] += v1 * v1;
        }
#pragma unroll
    for (int m = 1; m < 16; m <<= 1)
#pragma unroll
        for (int q = 0; q < 4; ++q) {
            s0[q] += __shfl_xor(s0[q], m); q0[q] += __shfl_xor(q0[q], m);
            s1[q] += __shfl_xor(s1[q], m); q1[q] += __shfl_xor(q1[q], m);
        }
    if (arow == 0) {
#pragma unroll
        for (int q = 0; q < 4; ++q) {
            int rw0 = wr * 32 + kgrp * 4 + q;
            rsums[wc][0][rw0] = s0[q]; rsums[wc][1][rw0] = q0[q];
            rsums[wc][0][rw0 + 16] = s1[q]; rsums[wc][1][rw0 + 16] = q1[q];
        }
    }
    __syncthreads();

    float mean0[4], rstd0[4], mean1[4], rstd1[4];
#pragma unroll
    for (int q = 0; q < 4; ++q) {
        int rw0 = wr * 32 + kgrp * 4 + q;
        float sm = rsums[0][0][rw0] + rsums[1][0][rw0];
        float sq = rsums[0][1][rw0] + rsums[1][1][rw0];
        mean0[q] = sm * (1.f / HID);
        rstd0[q] = rsqrtf(sq * (1.f / HID) - mean0[q] * mean0[q] + 1e-5f);
        int rw1 = rw0 + 16;
        sm = rsums[0][0][rw1] + rsums[1][0][rw1];
        sq = rsums[0][1][rw1] + rsums[1][1][rw1];
        mean1[q] = sm * (1.f / HID);
        rstd1[q] = rsqrtf(sq * (1.f / HID) - mean1[q] * mean1[q] + 1e-5f);
    }

    // LN apply + residual into regs; hn bf16 -> Abuf (swizzled)
#pragma unroll
    for (int ntl = 0; ntl < 4; ++ntl) {
        int col = wc * 64 + ntl * 16 + arow;
        int slotA = col >> 3, clA = col & 7;
#pragma unroll
        for (int q = 0; q < 4; ++q) {
            int rw0 = wr * 32 + kgrp * 4 + q;
            int row0 = tile0 + rw0;
            float u0 = fmaxf((c0[ntl][q] - mean0[q]) * rstd0[q] * gm[ntl] + bt[ntl], 0.f);
            float hr0 = (!first_layer && row0 < N_NODES) ? g_h[(size_t)row0 * HID + col] : 0.f;
            float hn0 = first_layer ? u0 : (hr0 + u0);
            c0[ntl][q] = hn0;
            Abuf[rw0 * 128 + ((slotA ^ (rw0 & 7)) << 3) + clA] = f2bf(hn0);
            int rw1 = rw0 + 16;
            int row1 = row0 + 16;
            float u1 = fmaxf((c1[ntl][q] - mean1[q]) * rstd1[q] * gm[ntl] + bt[ntl], 0.f);
            float hr1 = (!first_layer && row1 < N_NODES) ? g_h[(size_t)row1 * HID + col] : 0.f;
            float hn1 = first_layer ? u1 : (hr1 + u1);
            c1[ntl][q] = hn1;
            Abuf[rw1 * 128 + ((slotA ^ (rw1 & 7)) << 3) + clA] = f2bf(hn1);
        }
    }
    __syncthreads();   // Abuf(hn bf16) complete; Hbuf free

    // f32 h copy-out via Hbuf, two half-row passes (coalesced 128B stores)
    float* FB = (float*)Hbuf;  // 32 rows x 128 f32 = 16KB
#pragma unroll
    for (int h = 0; h < 2; ++h) {
        if (wr == h) {
#pragma unroll
            for (int ntl = 0; ntl < 4; ++ntl) {
                int col = wc * 64 + ntl * 16 + arow;
#pragma unroll
                for (int q = 0; q < 4; ++q) {
                    int lr = kgrp * 4 + q;
                    FB[lr * 128 + col] = c0[ntl][q];
                    FB[(lr + 16) * 128 + col] = c1[ntl][q];
                }
            }
        }
        __syncthreads();
#pragma unroll
        for (int i = 0; i < 4; ++i) {
            int pos = t + i * 256;          // 0..1023 float4 slots
            int row = pos >> 5, cc = pos & 31;
            int n = tile0 + h * 32 + row;
            if (n < N_NODES)
                *(float4*)&g_h[(size_t)n * HID + cc * 4] = *(const float4*)&FB[row * 128 + cc * 4];
        }
        __syncthreads();
    }

    if (Lpq < 0) return;   // last layer: nothing consumes hb or PQ

    // hb copy-out from Abuf (coalesced)
#pragma unroll
    for (int i = 0; i < 4; ++i) {
        int pos = t + i * 256;              // 0..1023 16B slots
        int row = pos >> 4, s = pos & 15;
        int n = tile0 + row;
        if (n < N_NODES)
            *(uint4*)&g_hb[(size_t)n * HID + s * 8] =
                *(const uint4*)&Abuf[row * 128 + ((s ^ (row & 7)) << 3)];
    }

    // GEMM3: PQ = hn @ pqw[Lpq], N=256 in two 128-col halves via Hbuf
    const unsigned short* wp = g_pqw + (size_t)Lpq * 4 * 16 * 64 * 8;
#pragma unroll
    for (int h = 0; h < 2; ++h) {
        bf16x8 w3[4][2];
#pragma unroll
        for (int ks = 0; ks < 4; ++ks)
#pragma unroll
            for (int j = 0; j < 2; ++j) {
                int nt = h * 8 + wave * 2 + j;
                w3[ks][j] = *(const bf16x8*)&wp[((size_t)(ks * 16 + nt) * 64 + lane) * 8];
            }
        f32x4 a3[4][2];
#pragma unroll
        for (int rf = 0; rf < 4; ++rf)
#pragma unroll
            for (int j = 0; j < 2; ++j) a3[rf][j] = (f32x4){0.f, 0.f, 0.f, 0.f};
#pragma unroll
        for (int ks = 0; ks < 4; ++ks) {
            int slot = ks * 4 + kgrp;
#pragma unroll
            for (int rf = 0; rf < 4; ++rf) {
                int row = rf * 16 + arow;
                bf16x8 a = *(const bf16x8*)&Abuf[row * 128 + ((slot ^ (arow & 7)) << 3)];
#pragma unroll
                for (int j = 0; j < 2; ++j)
                    a3[rf][j] = __builtin_amdgcn_mfma_f32_16x16x32_bf16(a, w3[ks][j], a3[rf][j], 0, 0, 0);
            }
        }
        __syncthreads();   // Hbuf free (prev readers done)
#pragma unroll
        for (int rf = 0; rf < 4; ++rf)
#pragma unroll
            for (int j = 0; j < 2; ++j) {
                int cl2 = (wave * 2 + j) * 16 + arow;
                int slotP = cl2 >> 3, clP = cl2 & 7;
#pragma unroll
                for (int q = 0; q < 4; ++q) {
                    int row = rf * 16 + kgrp * 4 + q;
                    Hbuf[row * 128 + ((slotP ^ (row & 7)) << 3) + clP] = f2bf(a3[rf][j][q]);
                }
            }
        __syncthreads();
#pragma unroll
        for (int i = 0; i < 4; ++i) {
            int u = t + i * 256;
            int row = u >> 4, s = u & 15;
            int n2 = tile0 + row;
            if (n2 < N_NODES)
                *(uint4*)&g_PQ[(size_t)n2 * 256 + h * 128 + s * 8] =
                    *(const uint4*)&Hbuf[row * 128 + ((s ^ (row & 7)) << 3)];
        }
    }
}

// ---------------- global mean pool: 8 blocks per graph, atomic partials ----------------
__global__ __launch_bounds__(256, 8)
void pool_k(const int* __restrict__ batch) {
    __shared__ int se[2];
    __shared__ float part[2][128];
    int b = blockIdx.x;
    int g = b >> 3, sub = b & 7;
    int t = threadIdx.x;
    if (t == 0) {
        int lo = 0, hi = N_NODES;
        while (lo < hi) { int m = (lo + hi) >> 1; if (batch[m] < g) lo = m + 1; else hi = m; }
        se[0] = lo;
        hi = N_NODES;
        while (lo < hi) { int m = (lo + hi) >> 1; if (batch[m] < g + 1) lo = m + 1; else hi = m; }
        se[1] = lo;
    }
    __syncthreads();
    int s = se[0], e = se[1];
    int c = t & 127, half = t >> 7;
    float acc = 0.f;
    for (int n = s + sub * 2 + half; n < e; n += 16) acc += g_h[(size_t)n * HID + c];
    part[half][c] = acc;
    __syncthreads();
    if (t < 128) {
        float v = part[0][t] + part[1][t];
        atomicAdd(&g_pooled[g * HID + t], v);
    }
}

// ---------------- readout MLP (divides pooled sums by graph size) ----------------
__global__ void readout_k(const int* __restrict__ batch,
                          const float* __restrict__ w1, const float* __restrict__ b1,
                          const float* __restrict__ w2, const float* __restrict__ b2,
                          const float* __restrict__ w3, const float* __restrict__ b3,
                          float* __restrict__ out) {
    __shared__ float p[128], o1[128], o2[64];
    __shared__ int se[2];
    int g = blockIdx.x, t = threadIdx.x;
    if (t == 0) {
        int lo = 0, hi = N_NODES;
        while (lo < hi) { int m = (lo + hi) >> 1; if (batch[m] < g) lo = m + 1; else hi = m; }
        se[0] = lo;
        hi = N_NODES;
        while (lo < hi) { int m = (lo + hi) >> 1; if (batch[m] < g + 1) lo = m + 1; else hi = m; }
        se[1] = lo;
    }
    __syncthreads();
    float cntf = fmaxf((float)(se[1] - se[0]), 1.f);
    p[t] = g_pooled[g * HID + t] / cntf;
    __syncthreads();
    float a = b1[t];
    for (int k = 0; k < 128; ++k) a += p[k] * w1[k * 128 + t];
    o1[t] = fmaxf(a, 0.f);
    __syncthreads();
    if (t < 64) {
        float a2 = b2[t];
        for (int k = 0; k < 128; ++k) a2 += o1[k] * w2[k * 64 + t];
        o2[t] = fmaxf(a2, 0.f);
    }
    __syncthreads();
    if (t == 0) {
        float a3 = b3[0];
        for (int k = 0; k < 64; ++k) a3 += o2[k] * w3[k];
        out[g] = a3;
    }
}

extern "C" void kernel_launch(void* const* d_in, const int* in_sizes, int n_in,
                              void* d_out, int out_size, void* d_ws, size_t ws_size,
                              hipStream_t stream) {
    const float* x     = (const float*)d_in[0];
    const int*   ei    = (const int*)d_in[1];
    const float* pos   = (const float*)d_in[3];
    const int*   batch = (const int*)d_in[4];
    const float* enc_w = (const float*)d_in[5];
    const float* enc_b = (const float*)d_in[6];
    const float* msg_w1 = (const float*)d_in[9];
    const float* msg_b1 = (const float*)d_in[10];
    const float* msg_w2 = (const float*)d_in[11];
    const float* msg_b2 = (const float*)d_in[12];
    const float* upd_w1 = (const float*)d_in[13];
    const float* upd_b1 = (const float*)d_in[14];
    const float* upd_w2 = (const float*)d_in[15];
    const float* upd_b2 = (const float*)d_in[16];
    const float* ln_g   = (const float*)d_in[17];
    const float* ln_b   = (const float*)d_in[18];
    const float* mw1 = (const float*)d_in[19];
    const float* mb1 = (const float*)d_in[20];
    const float* mw2 = (const float*)d_in[21];
    const float* mb2 = (const float*)d_in[22];
    const float* mw3 = (const float*)d_in[23];
    const float* mb3 = (const float*)d_in[24];
    float* out = (float*)d_out;
    (void)d_ws; (void)ws_size; (void)in_sizes; (void)n_in; (void)out_size;

    // weight preprocessing
    pack_pqw_k<<<NLAYERS * 4 * 16, 64, 0, stream>>>(msg_w1);
    wc_k<<<NLAYERS * 128, 128, 0, stream>>>(msg_w2, upd_w1);
    bc_k<<<NLAYERS, 128, 0, stream>>>(msg_b2, upd_w1);
    pack_u1_k<<<NLAYERS * 8 * 8, 64, 0, stream>>>(upd_w1);
    pack_w2_k<<<NLAYERS * 4 * 8, 64, 0, stream>>>(upd_w2);

    encode_k<<<N_NODES / 2, 256, 0, stream>>>(x, enc_w, enc_b);

    clear_cnt_k<<<(N_NODES + 255) / 256, 256, 0, stream>>>();
    hist_k<<<(N_EDGES + 255) / 256, 256, 0, stream>>>(ei);
    int nb = (N_NODES + 511) / 512;
    scanA_k<<<nb, 512, 0, stream>>>();
    scanB_k<<<1, 64, 0, stream>>>(nb);
    scanC_k<<<nb, 512, 0, stream>>>();
    scatter_k<<<(N_EDGES + 255) / 256, 256, 0, stream>>>(ei, pos);

    pq_k<<<NTILES, 256, 0, stream>>>(0);
    clear_pooled_k<<<32, 256, 0, stream>>>();
    for (int L = 0; L < NLAYERS; ++L) {
        edge_relu_k<<<EBLOCKS, 256, 0, stream>>>(
            msg_w1 + (size_t)L * 257 * HID + 256 * HID, msg_b1 + L * HID);
        upd_k<<<NTILES, 256, 0, stream>>>(
            upd_b1 + L * HID, upd_b2 + L * HID, ln_g + L * HID, ln_b + L * HID,
            L, L == 0 ? 1 : 0, L < NLAYERS - 1 ? L + 1 : -1);
    }

    pool_k<<<NGRAPHS * 8, 256, 0, stream>>>(batch);
    readout_k<<<NGRAPHS, 128, 0, stream>>>(batch, mw1, mb1, mw2, mb2, mw3, mb3, out);
}